// Round 1
// baseline (424.623 us; speedup 1.0000x reference)
//
#include <hip/hip_runtime.h>
#include <hip/hip_bf16.h>

// Problem: B=4, N=2048, D_MODEL=512, H=4, DK=64, DV=128. All fp32 in/out.
// Strategy: bf16 MFMA everywhere (no fp32 MFMA on CDNA4), fp32 accumulate.
// Softmax is over the BATCH axis (4 values) -> fully in-register per lane.

typedef __attribute__((ext_vector_type(8))) short short8;   // 8 x bf16 (4 VGPRs)
typedef __attribute__((ext_vector_type(4))) float floatx4;  // MFMA 16x16 acc
typedef unsigned short u16;

#define MFMA16(a, b, c) __builtin_amdgcn_mfma_f32_16x16x32_bf16((a), (b), (c), 0, 0, 0)

__device__ __forceinline__ u16 f2bf(float f) {
    union { float f; unsigned u; } v; v.f = f;
    unsigned r = v.u + 0x7fffu + ((v.u >> 16) & 1u);  // RNE
    return (u16)(r >> 16);
}

// ---------------- cast X: fp32 -> bf16, 4M elements ----------------
__global__ __launch_bounds__(256) void cast_x_kernel(const float* __restrict__ x,
                                                     u16* __restrict__ xb) {
    int i = blockIdx.x * 256 + threadIdx.x;  // 1,048,576 float4 groups exactly
    float4 v = ((const float4*)x)[i];
    ushort4 o;
    o.x = f2bf(v.x); o.y = f2bf(v.y); o.z = f2bf(v.z); o.w = f2bf(v.w);
    ((ushort4*)xb)[i] = o;
}

// ------- weights: fp32 [K][N] -> bf16 transposed [N][K]; Wq|Wk fused -------
__global__ __launch_bounds__(256) void prep_w_kernel(
    const float* __restrict__ Wq, const float* __restrict__ Wk,
    const float* __restrict__ Wv, const float* __restrict__ Wo,
    u16* __restrict__ WqkT, u16* __restrict__ WvT, u16* __restrict__ WoT) {
    int i = blockIdx.x * 256 + threadIdx.x;  // 3 * 512*512 = 786432 exactly
    int plane = i >> 18;
    int j = i & 0x3FFFF;
    int n = j >> 9, k = j & 511;
    if (plane == 0) {
        float v = (n < 256) ? Wq[k * 256 + n] : Wk[k * 256 + (n - 256)];
        WqkT[j] = f2bf(v);
    } else if (plane == 1) {
        WvT[j] = f2bf(Wv[k * 512 + n]);
    } else {
        WoT[j] = f2bf(Wo[k * 512 + n]);
    }
}

// ---------------- GEMM: C[M][N] = A[M][K] * BT[N][K]^T ----------------
// A, BT row-major bf16 with K contiguous. 128x128 tile, 4 waves in 2x2,
// each wave a 64x64 quadrant (4x4 c-frags of 16x16x32 MFMA). BK=64.
// LDS rows padded to 72 elements (36 dwords, == 4 mod 8) so a/b-frag reads
// (16 lanes hitting 16 rows) spread across banks instead of 16-way conflict.
__global__ __launch_bounds__(256) void gemm_bt_kernel(
    const u16* __restrict__ A, const u16* __restrict__ BT,
    void* __restrict__ Cout, int Kdim, int ldc, int store_f32) {
    __shared__ u16 Asl[128 * 72];
    __shared__ u16 Bsl[128 * 72];
    const int tid = threadIdx.x;
    const int mbase = blockIdx.y * 128;
    const int nbase = blockIdx.x * 128;
    const int wave = tid >> 6, lane = tid & 63;
    const int wm = wave >> 1, wn = wave & 1;
    const int lq = lane & 15, quad = lane >> 4;

    const floatx4 z4 = {0.f, 0.f, 0.f, 0.f};
    floatx4 acc[4][4];
#pragma unroll
    for (int i = 0; i < 4; i++)
#pragma unroll
        for (int j = 0; j < 4; j++) acc[i][j] = z4;

    const int nk = Kdim >> 6;
    for (int kk = 0; kk < nk; kk++) {
        const int kb = kk << 6;
        if (kk) __syncthreads();
#pragma unroll
        for (int i = 0; i < 4; i++) {  // stage 128x64 of A and BT (16KB each)
            int c = i * 256 + tid;
            int row = c >> 3, cc = (c & 7) << 3;
            *(short8*)&Asl[row * 72 + cc] =
                *(const short8*)&A[(mbase + row) * Kdim + kb + cc];
            *(short8*)&Bsl[row * 72 + cc] =
                *(const short8*)&BT[(nbase + row) * Kdim + kb + cc];
        }
        __syncthreads();
#pragma unroll
        for (int ki = 0; ki < 2; ki++) {
            short8 af[4], bf[4];
#pragma unroll
            for (int mi = 0; mi < 4; mi++)
                af[mi] = *(const short8*)&Asl[(wm * 64 + mi * 16 + lq) * 72 + ki * 32 + quad * 8];
#pragma unroll
            for (int ni = 0; ni < 4; ni++)
                bf[ni] = *(const short8*)&Bsl[(wn * 64 + ni * 16 + lq) * 72 + ki * 32 + quad * 8];
#pragma unroll
            for (int mi = 0; mi < 4; mi++)
#pragma unroll
                for (int ni = 0; ni < 4; ni++)
                    acc[mi][ni] = MFMA16(af[mi], bf[ni], acc[mi][ni]);
        }
    }
    // epilogue: C/D layout col=lane&15, row=quad*4+reg (verified m89/m91)
    if (store_f32) {
        float* C = (float*)Cout;
#pragma unroll
        for (int mi = 0; mi < 4; mi++)
#pragma unroll
            for (int ni = 0; ni < 4; ni++)
#pragma unroll
                for (int r = 0; r < 4; r++)
                    C[(mbase + wm * 64 + mi * 16 + quad * 4 + r) * ldc +
                      (nbase + wn * 64 + ni * 16 + lq)] = acc[mi][ni][r];
    } else {
        u16* C = (u16*)Cout;
#pragma unroll
        for (int mi = 0; mi < 4; mi++)
#pragma unroll
            for (int ni = 0; ni < 4; ni++)
#pragma unroll
                for (int r = 0; r < 4; r++)
                    C[(mbase + wm * 64 + mi * 16 + quad * 4 + r) * ldc +
                      (nbase + wn * 64 + ni * 16 + lq)] = f2bf(acc[mi][ni][r]);
    }
}

// ---------------- fused attention ----------------
// Grid: 256 WGs = (h in [0,4)) x (qtile of 32 rows, 64 tiles), XCD-swizzled so
// each head's K/V (~3MB) stays in one XCD's L2.
// Block: 4 waves; wave = (mi = q-sub16, half = dv-half & S key-half).
// Per k-step (64 keys): S = Q K^T for all 4 batches (16 MFMAs), softmax over
// batch in-register, p -> LDS (C-layout -> A-layout round-trip), PV (32 MFMAs).
__global__ __launch_bounds__(256) void attn_kernel(const u16* __restrict__ QK,
                                                   const u16* __restrict__ VT,
                                                   u16* __restrict__ AO) {
    __shared__ u16 pl[2 * 4 * 16 * 72];  // [mi][b][q 16][k padded 72], 18KB
    const int bx = blockIdx.x;
    const int xx = bx & 7;                       // XCD id (round-robin dispatch)
    const int h = xx & 3;                        // head pinned per XCD
    const int qt = ((bx >> 3) << 1) | (xx >> 2); // q-tile [0,64)
    const int tid = threadIdx.x;
    const int wave = tid >> 6, lane = tid & 63;
    const int mi = wave & 1, half = wave >> 1;
    const int lq = lane & 15, quad = lane >> 4;
    const int q0 = qt * 32 + mi * 16;

    // Q a-frags, persistent: A[m=lane&15][k=quad*8+j] (verified m120)
    short8 aq[4][2];
#pragma unroll
    for (int b = 0; b < 4; b++)
#pragma unroll
        for (int ki = 0; ki < 2; ki++)
            aq[b][ki] = *(const short8*)&QK[(b * 2048 + q0 + lq) * 512 +
                                            h * 64 + ki * 32 + quad * 8];

    const floatx4 z4 = {0.f, 0.f, 0.f, 0.f};
    floatx4 oacc[4][4];
#pragma unroll
    for (int b = 0; b < 4; b++)
#pragma unroll
        for (int ni = 0; ni < 4; ni++) oacc[b][ni] = z4;

    u16* plw = &pl[mi * (4 * 16 * 72)];

    for (int kt = 0; kt < 32; kt++) {
        const int kbase = kt * 64;
        // ---- S = Q K^T / 8, this wave's 32-key half, all 4 batches ----
        floatx4 s[4][2];
#pragma unroll
        for (int b = 0; b < 4; b++) {
#pragma unroll
            for (int nj = 0; nj < 2; nj++) {
                s[b][nj] = z4;
#pragma unroll
                for (int ki = 0; ki < 2; ki++) {
                    short8 bk = *(const short8*)&QK[
                        (b * 2048 + kbase + (half * 2 + nj) * 16 + lq) * 512 +
                        256 + h * 64 + ki * 32 + quad * 8];
                    s[b][nj] = MFMA16(aq[b][ki], bk, s[b][nj]);
                }
            }
        }
        // ---- softmax over batch (4 values, same lane/reg in 4 accs) ----
#pragma unroll
        for (int nj = 0; nj < 2; nj++) {
#pragma unroll
            for (int r = 0; r < 4; r++) {
                float v0 = s[0][nj][r] * 0.125f;
                float v1 = s[1][nj][r] * 0.125f;
                float v2 = s[2][nj][r] * 0.125f;
                float v3 = s[3][nj][r] * 0.125f;
                float mx = fmaxf(fmaxf(v0, v1), fmaxf(v2, v3));
                float e0 = __expf(v0 - mx), e1 = __expf(v1 - mx);
                float e2 = __expf(v2 - mx), e3 = __expf(v3 - mx);
                float inv = 1.f / (e0 + e1 + e2 + e3);
                int q = quad * 4 + r;
                int kcol = (half * 2 + nj) * 16 + lq;
                plw[(0 * 16 + q) * 72 + kcol] = f2bf(e0 * inv);
                plw[(1 * 16 + q) * 72 + kcol] = f2bf(e1 * inv);
                plw[(2 * 16 + q) * 72 + kcol] = f2bf(e2 * inv);
                plw[(3 * 16 + q) * 72 + kcol] = f2bf(e3 * inv);
            }
        }
        __syncthreads();
        // ---- O += P V  (p from LDS in A-layout, V^T gives k-contig B-frags)
#pragma unroll
        for (int b = 0; b < 4; b++) {
            short8 ap0 = *(const short8*)&plw[(b * 16 + lq) * 72 + quad * 8];
            short8 ap1 = *(const short8*)&plw[(b * 16 + lq) * 72 + 32 + quad * 8];
#pragma unroll
            for (int ni = 0; ni < 4; ni++) {
                const u16* vp = &VT[(h * 128 + half * 64 + ni * 16 + lq) * 8192 +
                                    b * 2048 + kbase + quad * 8];
                short8 bv0 = *(const short8*)vp;
                short8 bv1 = *(const short8*)(vp + 32);
                oacc[b][ni] = MFMA16(ap0, bv0, oacc[b][ni]);
                oacc[b][ni] = MFMA16(ap1, bv1, oacc[b][ni]);
            }
        }
        __syncthreads();  // protect pl before next iteration's writes
    }
    // ---- epilogue: AO[b*2048 + q][h*128 + d] bf16 ----
#pragma unroll
    for (int b = 0; b < 4; b++)
#pragma unroll
        for (int ni = 0; ni < 4; ni++)
#pragma unroll
            for (int r = 0; r < 4; r++)
                AO[(b * 2048 + q0 + quad * 4 + r) * 512 +
                   h * 128 + half * 64 + ni * 16 + lq] = f2bf(oacc[b][ni][r]);
}

extern "C" void kernel_launch(void* const* d_in, const int* in_sizes, int n_in,
                              void* d_out, int out_size, void* d_ws, size_t ws_size,
                              hipStream_t stream) {
    const float* x  = (const float*)d_in[0];
    const float* Wq = (const float*)d_in[1];
    const float* Wk = (const float*)d_in[2];
    const float* Wv = (const float*)d_in[3];
    const float* Wo = (const float*)d_in[4];
    float* out = (float*)d_out;

    char* ws = (char*)d_ws;
    u16* Xb   = (u16*)ws; ws += (size_t)8192 * 512 * 2;  // X bf16
    u16* WqkT = (u16*)ws; ws += (size_t)512 * 512 * 2;   // [Wq|Wk]^T bf16
    u16* WvT  = (u16*)ws; ws += (size_t)512 * 512 * 2;
    u16* WoT  = (u16*)ws; ws += (size_t)512 * 512 * 2;
    u16* QK   = (u16*)ws; ws += (size_t)8192 * 512 * 2;  // cols 0:256=Q, 256:512=K
    u16* VT   = (u16*)ws; ws += (size_t)8192 * 512 * 2;  // V^T [512][8192]
    u16* AO   = (u16*)ws; ws += (size_t)8192 * 512 * 2;  // attention out
    // total ~33.5 MB of d_ws

    cast_x_kernel<<<4096, 256, 0, stream>>>(x, Xb);
    prep_w_kernel<<<3072, 256, 0, stream>>>(Wq, Wk, Wv, Wo, WqkT, WvT, WoT);
    // QK = X @ [Wq|Wk] : [8192,512]
    gemm_bt_kernel<<<dim3(4, 64), 256, 0, stream>>>(Xb, WqkT, QK, 512, 512, 0);
    // V^T = Wv^T @ X^T : [512,8192]  (same kernel, swapped operands)
    gemm_bt_kernel<<<dim3(64, 4), 256, 0, stream>>>(WvT, Xb, VT, 512, 8192, 0);
    attn_kernel<<<256, 256, 0, stream>>>(QK, VT, AO);
    // out = AO @ Wo : fp32
    gemm_bt_kernel<<<dim3(4, 64), 256, 0, stream>>>(AO, WoT, out, 512, 512, 1);
}

// Round 2
// 365.188 us; speedup vs baseline: 1.1628x; 1.1628x over previous
//
#include <hip/hip_runtime.h>
#include <hip/hip_bf16.h>

// Problem: B=4, N=2048, D_MODEL=512, H=4, DK=64, DV=128. All fp32 in/out.
// bf16 MFMA everywhere (no fp32 MFMA on CDNA4), fp32 accumulate.
// Softmax is over the BATCH axis (4 values) -> fully in-register per lane.
// R2: attention was latency-bound at 11.5% occupancy (256 WGs). Split key
// range into 4 chunks (grid 1024), partial-O via fp32 atomicAdd, packed
// ds_write_b32 p-exchange via key remap (key = half*32 + 2*lq + nj).

typedef __attribute__((ext_vector_type(8))) short short8;   // 8 x bf16 (4 VGPRs)
typedef __attribute__((ext_vector_type(4))) float floatx4;  // MFMA 16x16 acc
typedef unsigned short u16;
typedef unsigned int u32;

#define MFMA16(a, b, c) __builtin_amdgcn_mfma_f32_16x16x32_bf16((a), (b), (c), 0, 0, 0)

__device__ __forceinline__ u16 f2bf(float f) {
    union { float f; unsigned u; } v; v.f = f;
    unsigned r = v.u + 0x7fffu + ((v.u >> 16) & 1u);  // RNE
    return (u16)(r >> 16);
}

// ---------------- cast fp32 -> bf16, 4M elements (X, and later AOf->AO) ----
__global__ __launch_bounds__(256) void cast_x_kernel(const float* __restrict__ x,
                                                     u16* __restrict__ xb) {
    int i = blockIdx.x * 256 + threadIdx.x;  // 1,048,576 float4 groups exactly
    float4 v = ((const float4*)x)[i];
    ushort4 o;
    o.x = f2bf(v.x); o.y = f2bf(v.y); o.z = f2bf(v.z); o.w = f2bf(v.w);
    ((ushort4*)xb)[i] = o;
}

// ------- weights: fp32 [K][N] -> bf16 transposed [N][K]; Wq|Wk fused -------
__global__ __launch_bounds__(256) void prep_w_kernel(
    const float* __restrict__ Wq, const float* __restrict__ Wk,
    const float* __restrict__ Wv, const float* __restrict__ Wo,
    u16* __restrict__ WqkT, u16* __restrict__ WvT, u16* __restrict__ WoT) {
    int i = blockIdx.x * 256 + threadIdx.x;  // 3 * 512*512 = 786432 exactly
    int plane = i >> 18;
    int j = i & 0x3FFFF;
    int n = j >> 9, k = j & 511;
    if (plane == 0) {
        float v = (n < 256) ? Wq[k * 256 + n] : Wk[k * 256 + (n - 256)];
        WqkT[j] = f2bf(v);
    } else if (plane == 1) {
        WvT[j] = f2bf(Wv[k * 512 + n]);
    } else {
        WoT[j] = f2bf(Wo[k * 512 + n]);
    }
}

// ---------------- GEMM: C[M][N] = A[M][K] * BT[N][K]^T ----------------
// A, BT row-major bf16 with K contiguous. 128x128 tile, 4 waves in 2x2,
// each wave a 64x64 quadrant (4x4 c-frags of 16x16x32 MFMA). BK=64.
__global__ __launch_bounds__(256) void gemm_bt_kernel(
    const u16* __restrict__ A, const u16* __restrict__ BT,
    void* __restrict__ Cout, int Kdim, int ldc, int store_f32) {
    __shared__ u16 Asl[128 * 72];
    __shared__ u16 Bsl[128 * 72];
    const int tid = threadIdx.x;
    const int mbase = blockIdx.y * 128;
    const int nbase = blockIdx.x * 128;
    const int wave = tid >> 6, lane = tid & 63;
    const int wm = wave >> 1, wn = wave & 1;
    const int lq = lane & 15, quad = lane >> 4;

    const floatx4 z4 = {0.f, 0.f, 0.f, 0.f};
    floatx4 acc[4][4];
#pragma unroll
    for (int i = 0; i < 4; i++)
#pragma unroll
        for (int j = 0; j < 4; j++) acc[i][j] = z4;

    const int nk = Kdim >> 6;
    for (int kk = 0; kk < nk; kk++) {
        const int kb = kk << 6;
        if (kk) __syncthreads();
#pragma unroll
        for (int i = 0; i < 4; i++) {  // stage 128x64 of A and BT (16KB each)
            int c = i * 256 + tid;
            int row = c >> 3, cc = (c & 7) << 3;
            *(short8*)&Asl[row * 72 + cc] =
                *(const short8*)&A[(mbase + row) * Kdim + kb + cc];
            *(short8*)&Bsl[row * 72 + cc] =
                *(const short8*)&BT[(nbase + row) * Kdim + kb + cc];
        }
        __syncthreads();
#pragma unroll
        for (int ki = 0; ki < 2; ki++) {
            short8 af[4], bf[4];
#pragma unroll
            for (int mi = 0; mi < 4; mi++)
                af[mi] = *(const short8*)&Asl[(wm * 64 + mi * 16 + lq) * 72 + ki * 32 + quad * 8];
#pragma unroll
            for (int ni = 0; ni < 4; ni++)
                bf[ni] = *(const short8*)&Bsl[(wn * 64 + ni * 16 + lq) * 72 + ki * 32 + quad * 8];
#pragma unroll
            for (int mi = 0; mi < 4; mi++)
#pragma unroll
                for (int ni = 0; ni < 4; ni++)
                    acc[mi][ni] = MFMA16(af[mi], bf[ni], acc[mi][ni]);
        }
    }
    // epilogue: C/D layout col=lane&15, row=quad*4+reg (verified m89/m91)
    if (store_f32) {
        float* C = (float*)Cout;
#pragma unroll
        for (int mi = 0; mi < 4; mi++)
#pragma unroll
            for (int ni = 0; ni < 4; ni++)
#pragma unroll
                for (int r = 0; r < 4; r++)
                    C[(mbase + wm * 64 + mi * 16 + quad * 4 + r) * ldc +
                      (nbase + wn * 64 + ni * 16 + lq)] = acc[mi][ni][r];
    } else {
        u16* C = (u16*)Cout;
#pragma unroll
        for (int mi = 0; mi < 4; mi++)
#pragma unroll
            for (int ni = 0; ni < 4; ni++)
#pragma unroll
                for (int r = 0; r < 4; r++)
                    C[(mbase + wm * 64 + mi * 16 + quad * 4 + r) * ldc +
                      (nbase + wn * 64 + ni * 16 + lq)] = f2bf(acc[mi][ni][r]);
    }
}

// ---------------- fused attention (key-chunked) ----------------
// Grid: 1024 WGs = h(4) x chunk(4) x qtile(64 of 32 rows). bx&3 = h keeps a
// head's K/V (~2-3MB) within the XCD pair's L2. Each WG handles kt in
// [c*8, c*8+8) (512 keys) and atomicAdds partial O (fp32) into AOf.
// Block: 4 waves; wave = (mi = q-sub16, half = dv-half & S key-half).
// Key remap within kt step: key = kbase + half*32 + 2*lq + nj, so the two
// nj p-values per lane are k-adjacent -> single packed ds_write_b32; the
// plw column c holds key kbase+c (identity), so PV's V reads are unchanged.
__global__ __launch_bounds__(256) void attn_kernel(const u16* __restrict__ QK,
                                                   const u16* __restrict__ VT,
                                                   float* __restrict__ AOf) {
    __shared__ u16 pl[2 * 4 * 16 * 72];  // [mi][b][q 16][k padded 72], 18KB
    const int bx = blockIdx.x;
    const int h = bx & 3;
    const int ck = (bx >> 2) & 3;                // key chunk
    const int qt = bx >> 4;                      // q-tile [0,64)
    const int tid = threadIdx.x;
    const int wave = tid >> 6, lane = tid & 63;
    const int mi = wave & 1, half = wave >> 1;
    const int lq = lane & 15, quad = lane >> 4;
    const int q0 = qt * 32 + mi * 16;

    // Q a-frags, persistent: A[m=lane&15][k=quad*8+j] (verified m120)
    short8 aq[4][2];
#pragma unroll
    for (int b = 0; b < 4; b++)
#pragma unroll
        for (int ki = 0; ki < 2; ki++)
            aq[b][ki] = *(const short8*)&QK[(b * 2048 + q0 + lq) * 512 +
                                            h * 64 + ki * 32 + quad * 8];

    const floatx4 z4 = {0.f, 0.f, 0.f, 0.f};
    floatx4 oacc[4][4];
#pragma unroll
    for (int b = 0; b < 4; b++)
#pragma unroll
        for (int ni = 0; ni < 4; ni++) oacc[b][ni] = z4;

    u16* plw = &pl[mi * (4 * 16 * 72)];

    for (int kt = ck * 8; kt < ck * 8 + 8; kt++) {
        const int kbase = kt * 64;
        // ---- S = Q K^T / 8, this wave's 32-key half, all 4 batches ----
        // B-frag nj loads K row kbase + half*32 + 2*lq + nj.
        floatx4 s[4][2];
#pragma unroll
        for (int b = 0; b < 4; b++) {
#pragma unroll
            for (int nj = 0; nj < 2; nj++) {
                s[b][nj] = z4;
#pragma unroll
                for (int ki = 0; ki < 2; ki++) {
                    short8 bk = *(const short8*)&QK[
                        (b * 2048 + kbase + half * 32 + 2 * lq + nj) * 512 +
                        256 + h * 64 + ki * 32 + quad * 8];
                    s[b][nj] = MFMA16(aq[b][ki], bk, s[b][nj]);
                }
            }
        }
        // ---- softmax over batch (4 values, same lane/reg in 4 accs) ----
        // lane holds S[q=quad*4+r][key = kbase + half*32 + 2*lq + nj]
#pragma unroll
        for (int r = 0; r < 4; r++) {
            int q = quad * 4 + r;
            int col = half * 32 + 2 * lq;  // k-adjacent pair (nj=0,1)
            u32 pk[4];
#pragma unroll
            for (int nj = 0; nj < 2; nj++) {
                float v0 = s[0][nj][r] * 0.125f;
                float v1 = s[1][nj][r] * 0.125f;
                float v2 = s[2][nj][r] * 0.125f;
                float v3 = s[3][nj][r] * 0.125f;
                float mx = fmaxf(fmaxf(v0, v1), fmaxf(v2, v3));
                float e0 = __expf(v0 - mx), e1 = __expf(v1 - mx);
                float e2 = __expf(v2 - mx), e3 = __expf(v3 - mx);
                float inv = 1.f / (e0 + e1 + e2 + e3);
                u32 sh = nj * 16;
                u32 msk = 0xFFFFu << sh;
                pk[0] = (pk[0] & ~msk) | ((u32)f2bf(e0 * inv) << sh);
                pk[1] = (pk[1] & ~msk) | ((u32)f2bf(e1 * inv) << sh);
                pk[2] = (pk[2] & ~msk) | ((u32)f2bf(e2 * inv) << sh);
                pk[3] = (pk[3] & ~msk) | ((u32)f2bf(e3 * inv) << sh);
            }
#pragma unroll
            for (int b = 0; b < 4; b++)
                *(u32*)&plw[(b * 16 + q) * 72 + col] = pk[b];
        }
        __syncthreads();
        // ---- O += P V  (p from LDS in A-layout, V^T gives k-contig B-frags)
#pragma unroll
        for (int b = 0; b < 4; b++) {
            short8 ap0 = *(const short8*)&plw[(b * 16 + lq) * 72 + quad * 8];
            short8 ap1 = *(const short8*)&plw[(b * 16 + lq) * 72 + 32 + quad * 8];
#pragma unroll
            for (int ni = 0; ni < 4; ni++) {
                const u16* vp = &VT[(h * 128 + half * 64 + ni * 16 + lq) * 8192 +
                                    b * 2048 + kbase + quad * 8];
                short8 bv0 = *(const short8*)vp;
                short8 bv1 = *(const short8*)(vp + 32);
                oacc[b][ni] = MFMA16(ap0, bv0, oacc[b][ni]);
                oacc[b][ni] = MFMA16(ap1, bv1, oacc[b][ni]);
            }
        }
        __syncthreads();  // protect pl before next iteration's writes
    }
    // ---- epilogue: partial O -> fp32 atomicAdd into AOf[b*2048+q][h*128+d]
#pragma unroll
    for (int b = 0; b < 4; b++)
#pragma unroll
        for (int ni = 0; ni < 4; ni++)
#pragma unroll
            for (int r = 0; r < 4; r++)
                atomicAdd(&AOf[(b * 2048 + q0 + quad * 4 + r) * 512 +
                               h * 128 + half * 64 + ni * 16 + lq],
                          oacc[b][ni][r]);
}

extern "C" void kernel_launch(void* const* d_in, const int* in_sizes, int n_in,
                              void* d_out, int out_size, void* d_ws, size_t ws_size,
                              hipStream_t stream) {
    const float* x  = (const float*)d_in[0];
    const float* Wq = (const float*)d_in[1];
    const float* Wk = (const float*)d_in[2];
    const float* Wv = (const float*)d_in[3];
    const float* Wo = (const float*)d_in[4];
    float* out = (float*)d_out;

    char* ws = (char*)d_ws;
    u16* Xb   = (u16*)ws; ws += (size_t)8192 * 512 * 2;  // X bf16
    u16* WqkT = (u16*)ws; ws += (size_t)512 * 512 * 2;   // [Wq|Wk]^T bf16
    u16* WvT  = (u16*)ws; ws += (size_t)512 * 512 * 2;
    u16* WoT  = (u16*)ws; ws += (size_t)512 * 512 * 2;
    u16* QK   = (u16*)ws; ws += (size_t)8192 * 512 * 2;  // cols 0:256=Q, 256:512=K
    u16* VT   = (u16*)ws; ws += (size_t)8192 * 512 * 2;  // V^T [512][8192]
    u16* AO   = (u16*)ws; ws += (size_t)8192 * 512 * 2;  // attention out bf16
    float* AOf = (float*)ws; ws += (size_t)8192 * 512 * 4;  // fp32 accumulator
    // total ~50 MB of d_ws

    cast_x_kernel<<<4096, 256, 0, stream>>>(x, Xb);
    prep_w_kernel<<<3072, 256, 0, stream>>>(Wq, Wk, Wv, Wo, WqkT, WvT, WoT);
    // QK = X @ [Wq|Wk] : [8192,512]
    gemm_bt_kernel<<<dim3(4, 64), 256, 0, stream>>>(Xb, WqkT, QK, 512, 512, 0);
    // V^T = Wv^T @ X^T : [512,8192]  (same kernel, swapped operands)
    gemm_bt_kernel<<<dim3(64, 4), 256, 0, stream>>>(WvT, Xb, VT, 512, 8192, 0);
    hipMemsetAsync(AOf, 0, (size_t)8192 * 512 * 4, stream);
    attn_kernel<<<1024, 256, 0, stream>>>(QK, VT, AOf);
    cast_x_kernel<<<4096, 256, 0, stream>>>(AOf, AO);  // fp32 -> bf16
    // out = AO @ Wo : fp32
    gemm_bt_kernel<<<dim3(4, 64), 256, 0, stream>>>(AO, WoT, out, 512, 512, 1);
}

// Round 3
// 359.341 us; speedup vs baseline: 1.1817x; 1.0163x over previous
//
#include <hip/hip_runtime.h>
#include <hip/hip_bf16.h>

// B=4, N=2048, D_MODEL=512, H=4, DK=64, DV=128. fp32 in/out, bf16 MFMA.
// Softmax over BATCH axis (4 values) -> in-register per lane.
// R3: (1) K/V emitted by producer GEMMs in MFMA-fragment-major layout so all
// hot attn loads are coalesced (was 64-line gathers). (2) attention is
// barrier-free: each wave computes full-64-key S (dup x2), P round-trip via
// wave-private LDS. (3) GEMMs use 64x64 tiles -> 1024 WGs (were 256).

typedef __attribute__((ext_vector_type(8))) short short8;   // 8 x bf16
typedef __attribute__((ext_vector_type(4))) float floatx4;  // MFMA 16x16 acc
typedef unsigned short u16;
typedef unsigned int u32;

#define MFMA16(a, b, c) __builtin_amdgcn_mfma_f32_16x16x32_bf16((a), (b), (c), 0, 0, 0)

__device__ __forceinline__ u16 f2bf(float f) {
    union { float f; unsigned u; } v; v.f = f;
    unsigned r = v.u + 0x7fffu + ((v.u >> 16) & 1u);  // RNE
    return (u16)(r >> 16);
}

// ---------------- cast fp32 -> bf16 (X, and AOf -> AO) ----------------
__global__ __launch_bounds__(256) void cast_x_kernel(const float* __restrict__ x,
                                                     u16* __restrict__ xb) {
    int i = blockIdx.x * 256 + threadIdx.x;  // 1,048,576 float4 groups exactly
    float4 v = ((const float4*)x)[i];
    ushort4 o;
    o.x = f2bf(v.x); o.y = f2bf(v.y); o.z = f2bf(v.z); o.w = f2bf(v.w);
    ((ushort4*)xb)[i] = o;
}

// ------- weights: fp32 [K][N] -> bf16 transposed [N][K]; Wq|Wk fused -------
__global__ __launch_bounds__(256) void prep_w_kernel(
    const float* __restrict__ Wq, const float* __restrict__ Wk,
    const float* __restrict__ Wv, const float* __restrict__ Wo,
    u16* __restrict__ WqkT, u16* __restrict__ WvT, u16* __restrict__ WoT) {
    int i = blockIdx.x * 256 + threadIdx.x;  // 3 * 512*512 = 786432 exactly
    int plane = i >> 18;
    int j = i & 0x3FFFF;
    int n = j >> 9, k = j & 511;
    if (plane == 0) {
        float v = (n < 256) ? Wq[k * 256 + n] : Wk[k * 256 + (n - 256)];
        WqkT[j] = f2bf(v);
    } else if (plane == 1) {
        WvT[j] = f2bf(Wv[k * 512 + n]);
    } else {
        WoT[j] = f2bf(Wo[k * 512 + n]);
    }
}

// ---------------- GEMM: C[M][N] = A[M][K] * BT[N][K]^T, 64x64 tile --------
// 4 waves in 2x2, each wave 32x32 (2x2 c-frags). BK=64, LDS rows padded to 72.
// mode 1: fp32 plain (ldc). mode 2: Q plain [8192][256] + K fragment-packed.
// mode 3: V fragment-packed (C is conceptually V^T [512][8192]).
// Kp layout: ((((((b*4+h)*32+kt)*2+half)*2+nj)*2+ki)*64+lane)*8+j
//   <-> K[row=b*2048+kt*64+half*32+2*lq+nj][col=256+h*64+ki*32+quad*8+j]
// Vp layout: ((((((b*4+h)*32+kt)*2+half)*4+ni)*2+w)*64+lane)*8+j
//   <-> V[dv=h*128+half*64+ni*16+lq][key=kt*64+w*32+quad*8+j]
__global__ __launch_bounds__(256) void gemm64_kernel(
    const u16* __restrict__ A, const u16* __restrict__ BT,
    float* __restrict__ Cf, u16* __restrict__ Qb, u16* __restrict__ Cp,
    int Kdim, int ldc, int mode) {
    __shared__ u16 Asl[64 * 72];
    __shared__ u16 Bsl[64 * 72];
    const int tid = threadIdx.x;
    const int mbase = blockIdx.y * 64;
    const int nbase = blockIdx.x * 64;
    const int wave = tid >> 6, lane = tid & 63;
    const int wm = wave >> 1, wn = wave & 1;
    const int lq = lane & 15, quad = lane >> 4;

    const floatx4 z4 = {0.f, 0.f, 0.f, 0.f};
    floatx4 acc[2][2];
#pragma unroll
    for (int i = 0; i < 2; i++)
#pragma unroll
        for (int j = 0; j < 2; j++) acc[i][j] = z4;

    const int nk = Kdim >> 6;
    for (int kk = 0; kk < nk; kk++) {
        const int kb = kk << 6;
        if (kk) __syncthreads();
        {   // stage 64x64 of A and BT (8KB each): 2 short8 per thread each
            int row = tid >> 3, cc = (tid & 7) << 3;
            *(short8*)&Asl[row * 72 + cc] =
                *(const short8*)&A[(mbase + row) * Kdim + kb + cc];
            *(short8*)&Bsl[row * 72 + cc] =
                *(const short8*)&BT[(nbase + row) * Kdim + kb + cc];
            int c2 = 256 + tid;
            int row2 = c2 >> 3, cc2 = (c2 & 7) << 3;
            *(short8*)&Asl[row2 * 72 + cc2] =
                *(const short8*)&A[(mbase + row2) * Kdim + kb + cc2];
            *(short8*)&Bsl[row2 * 72 + cc2] =
                *(const short8*)&BT[(nbase + row2) * Kdim + kb + cc2];
        }
        __syncthreads();
#pragma unroll
        for (int ki = 0; ki < 2; ki++) {
            short8 af[2], bf[2];
#pragma unroll
            for (int mi = 0; mi < 2; mi++)
                af[mi] = *(const short8*)&Asl[(wm * 32 + mi * 16 + lq) * 72 + ki * 32 + quad * 8];
#pragma unroll
            for (int ni = 0; ni < 2; ni++)
                bf[ni] = *(const short8*)&Bsl[(wn * 32 + ni * 16 + lq) * 72 + ki * 32 + quad * 8];
#pragma unroll
            for (int mi = 0; mi < 2; mi++)
#pragma unroll
                for (int ni = 0; ni < 2; ni++)
                    acc[mi][ni] = MFMA16(af[mi], bf[ni], acc[mi][ni]);
        }
    }
    // epilogue: C/D layout col=lane&15, row=quad*4+reg (verified m89/m91)
    if (mode == 1) {
#pragma unroll
        for (int mi = 0; mi < 2; mi++)
#pragma unroll
            for (int ni = 0; ni < 2; ni++)
#pragma unroll
                for (int r = 0; r < 4; r++)
                    Cf[(mbase + wm * 32 + mi * 16 + quad * 4 + r) * ldc +
                       (nbase + wn * 32 + ni * 16 + lq)] = acc[mi][ni][r];
    } else if (mode == 2) {
        if (nbase < 256) {  // Q region: plain [8192][256] (uniform per block)
#pragma unroll
            for (int mi = 0; mi < 2; mi++)
#pragma unroll
                for (int ni = 0; ni < 2; ni++)
#pragma unroll
                    for (int r = 0; r < 4; r++)
                        Qb[(mbase + wm * 32 + mi * 16 + quad * 4 + r) * 256 +
                           (nbase + wn * 32 + ni * 16 + lq)] = f2bf(acc[mi][ni][r]);
        } else {  // K region -> fragment-packed
#pragma unroll
            for (int mi = 0; mi < 2; mi++)
#pragma unroll
                for (int ni = 0; ni < 2; ni++) {
                    int colk = nbase + wn * 32 + ni * 16 + lq - 256;  // [0,256)
                    int h = colk >> 6, dkc = colk & 63;
                    int ki = dkc >> 5, quadk = (dkc >> 3) & 3, j = dkc & 7;
#pragma unroll
                    for (int r = 0; r < 4; r++) {
                        int row = mbase + wm * 32 + mi * 16 + quad * 4 + r;
                        int b = row >> 11, key = row & 2047;
                        int kt = key >> 6, r6 = key & 63;
                        int half = r6 >> 5, r5 = r6 & 31;
                        int lqk = r5 >> 1, nj = r5 & 1;
                        int lane_k = quadk * 16 + lqk;
                        Cp[((((((((b * 4 + h) * 32 + kt) * 2 + half) * 2 + nj)
                               * 2 + ki) * 64 + lane_k) << 3) + j)] =
                            f2bf(acc[mi][ni][r]);
                    }
                }
        }
    } else {  // mode 3: V fragment-packed; C row = dv, col = b*2048+key
#pragma unroll
        for (int mi = 0; mi < 2; mi++) {
#pragma unroll
            for (int ni = 0; ni < 2; ni++) {
                int col = nbase + wn * 32 + ni * 16 + lq;
                int b = col >> 11, key = col & 2047;
                int kt = key >> 6, rr = key & 63;
                int w = rr >> 5, r5 = rr & 31;
                int quadv = r5 >> 3, j = r5 & 7;
#pragma unroll
                for (int r = 0; r < 4; r++) {
                    int dv = mbase + wm * 32 + mi * 16 + quad * 4 + r;
                    int h = dv >> 7, r7 = dv & 127;
                    int half = r7 >> 6, r6v = r7 & 63;
                    int niv = r6v >> 4, lqv = r6v & 15;
                    int lane_v = quadv * 16 + lqv;
                    Cp[((((((((b * 4 + h) * 32 + kt) * 2 + half) * 4 + niv)
                           * 2 + w) * 64 + lane_v) << 3) + j)] =
                        f2bf(acc[mi][ni][r]);
                }
            }
        }
    }
}

// ---------------- fused attention: barrier-free, coalesced ----------------
// Grid: 1024 WGs = h(bx&3) x chunk((bx>>2)&3) x qtile(bx>>4, 64 of 32 rows).
// Block: 4 waves; wave = (mi = q-sub16, half = dv-half). Each wave computes
// the FULL 64-key S for its 16 q rows (duplicated across half) -> the P
// C-layout -> A-layout LDS round-trip is wave-private -> NO __syncthreads.
__global__ __launch_bounds__(256) void attn_kernel(const u16* __restrict__ Qb,
                                                   const u16* __restrict__ Kp,
                                                   const u16* __restrict__ Vp,
                                                   float* __restrict__ AOf) {
    __shared__ u16 pl[4 * 4 * 16 * 72];  // per-wave private [b][q16][k72]
    const int bx = blockIdx.x;
    const int h = bx & 3;
    const int ck = (bx >> 2) & 3;
    const int qt = bx >> 4;
    const int tid = threadIdx.x;
    const int wave = tid >> 6, lane = tid & 63;
    const int mi = wave & 1, half = wave >> 1;
    const int lq = lane & 15, quad = lane >> 4;
    const int q0 = qt * 32 + mi * 16;

    // Q a-frags, persistent: A[m=lane&15][k=quad*8+j]
    short8 aq[4][2];
#pragma unroll
    for (int b = 0; b < 4; b++)
#pragma unroll
        for (int ki = 0; ki < 2; ki++)
            aq[b][ki] = *(const short8*)&Qb[(b * 2048 + q0 + lq) * 256 +
                                            h * 64 + ki * 32 + quad * 8];

    const floatx4 z4 = {0.f, 0.f, 0.f, 0.f};
    floatx4 oacc[4][4];
#pragma unroll
    for (int b = 0; b < 4; b++)
#pragma unroll
        for (int ni = 0; ni < 4; ni++) oacc[b][ni] = z4;

    u16* plw = &pl[wave * (4 * 16 * 72)];

    for (int kt = ck * 8; kt < ck * 8 + 8; kt++) {
        // ---- S = Q K^T for all 4 batches, all 64 keys (two 32-key halves)
#pragma unroll
        for (int h2 = 0; h2 < 2; h2++) {
            floatx4 s[4][2];
#pragma unroll
            for (int b = 0; b < 4; b++) {
                const u16* kb = Kp + ((size_t)((((b * 4 + h) * 32 + kt) * 2 + h2) * 2) << 10)
                                   + lane * 8;
#pragma unroll
                for (int nj = 0; nj < 2; nj++) {
                    s[b][nj] = z4;
#pragma unroll
                    for (int ki = 0; ki < 2; ki++)
                        s[b][nj] = MFMA16(aq[b][ki],
                                          *(const short8*)(kb + (nj * 2 + ki) * 512),
                                          s[b][nj]);
                }
            }
            // softmax over batch; lane holds S[q=quad*4+r][key=h2*32+2*lq+nj]
#pragma unroll
            for (int r = 0; r < 4; r++) {
                u32 pk[4];
#pragma unroll
                for (int nj = 0; nj < 2; nj++) {
                    float v0 = s[0][nj][r] * 0.125f;
                    float v1 = s[1][nj][r] * 0.125f;
                    float v2 = s[2][nj][r] * 0.125f;
                    float v3 = s[3][nj][r] * 0.125f;
                    float mx = fmaxf(fmaxf(v0, v1), fmaxf(v2, v3));
                    float e0 = __expf(v0 - mx), e1 = __expf(v1 - mx);
                    float e2 = __expf(v2 - mx), e3 = __expf(v3 - mx);
                    float inv = 1.f / (e0 + e1 + e2 + e3);
                    if (nj == 0) {
                        pk[0] = (u32)f2bf(e0 * inv);
                        pk[1] = (u32)f2bf(e1 * inv);
                        pk[2] = (u32)f2bf(e2 * inv);
                        pk[3] = (u32)f2bf(e3 * inv);
                    } else {
                        pk[0] |= (u32)f2bf(e0 * inv) << 16;
                        pk[1] |= (u32)f2bf(e1 * inv) << 16;
                        pk[2] |= (u32)f2bf(e2 * inv) << 16;
                        pk[3] |= (u32)f2bf(e3 * inv) << 16;
                    }
                }
                int q = quad * 4 + r, col = h2 * 32 + 2 * lq;
#pragma unroll
                for (int b = 0; b < 4; b++)
                    *(u32*)&plw[(b * 16 + q) * 72 + col] = pk[b];
            }
        }
        // ---- O += P V (wave-private LDS; compiler inserts lgkmcnt waits)
#pragma unroll
        for (int b = 0; b < 4; b++) {
            short8 ap0 = *(const short8*)&plw[(b * 16 + lq) * 72 + quad * 8];
            short8 ap1 = *(const short8*)&plw[(b * 16 + lq) * 72 + 32 + quad * 8];
            const u16* vb = Vp + ((size_t)((((b * 4 + h) * 32 + kt) * 2 + half) * 8) << 9)
                               + lane * 8;
#pragma unroll
            for (int ni = 0; ni < 4; ni++) {
                oacc[b][ni] = MFMA16(ap0, *(const short8*)(vb + (ni * 2 + 0) * 512),
                                     oacc[b][ni]);
                oacc[b][ni] = MFMA16(ap1, *(const short8*)(vb + (ni * 2 + 1) * 512),
                                     oacc[b][ni]);
            }
        }
    }
    // ---- epilogue: partial O -> fp32 atomicAdd into AOf[b*2048+q][h*128+d]
#pragma unroll
    for (int b = 0; b < 4; b++)
#pragma unroll
        for (int ni = 0; ni < 4; ni++)
#pragma unroll
            for (int r = 0; r < 4; r++)
                atomicAdd(&AOf[(b * 2048 + q0 + quad * 4 + r) * 512 +
                               h * 128 + half * 64 + ni * 16 + lq],
                          oacc[b][ni][r]);
}

extern "C" void kernel_launch(void* const* d_in, const int* in_sizes, int n_in,
                              void* d_out, int out_size, void* d_ws, size_t ws_size,
                              hipStream_t stream) {
    const float* x  = (const float*)d_in[0];
    const float* Wq = (const float*)d_in[1];
    const float* Wk = (const float*)d_in[2];
    const float* Wv = (const float*)d_in[3];
    const float* Wo = (const float*)d_in[4];
    float* out = (float*)d_out;

    char* ws = (char*)d_ws;
    u16* Xb   = (u16*)ws; ws += (size_t)8192 * 512 * 2;   // X bf16
    u16* WqkT = (u16*)ws; ws += (size_t)512 * 512 * 2;    // [Wq|Wk]^T bf16
    u16* WvT  = (u16*)ws; ws += (size_t)512 * 512 * 2;
    u16* WoT  = (u16*)ws; ws += (size_t)512 * 512 * 2;
    u16* Qb   = (u16*)ws; ws += (size_t)8192 * 256 * 2;   // Q plain [8192][256]
    u16* Kp   = (u16*)ws; ws += (size_t)8192 * 256 * 2;   // K fragment-packed
    u16* Vp   = (u16*)ws; ws += (size_t)8192 * 512 * 2;   // V fragment-packed
    u16* AO   = (u16*)ws; ws += (size_t)8192 * 512 * 2;   // attention out bf16
    float* AOf = (float*)ws; ws += (size_t)8192 * 512 * 4; // fp32 accumulator
    // total ~49.5 MB of d_ws

    cast_x_kernel<<<4096, 256, 0, stream>>>(x, Xb);
    prep_w_kernel<<<3072, 256, 0, stream>>>(Wq, Wk, Wv, Wo, WqkT, WvT, WoT);
    // QK = X @ [Wq|Wk] : [8192,512] -> Qb plain + Kp packed
    gemm64_kernel<<<dim3(8, 128), 256, 0, stream>>>(Xb, WqkT, nullptr, Qb, Kp, 512, 0, 2);
    // V^T = Wv^T @ X^T : [512,8192] -> Vp packed
    gemm64_kernel<<<dim3(128, 8), 256, 0, stream>>>(WvT, Xb, nullptr, nullptr, Vp, 512, 0, 3);
    hipMemsetAsync(AOf, 0, (size_t)8192 * 512 * 4, stream);
    attn_kernel<<<1024, 256, 0, stream>>>(Qb, Kp, Vp, AOf);
    cast_x_kernel<<<4096, 256, 0, stream>>>(AOf, AO);  // fp32 -> bf16
    // out = AO @ Wo : fp32
    gemm64_kernel<<<dim3(8, 128), 256, 0, stream>>>(AO, WoT, out, nullptr, nullptr, 512, 512, 1);
}

// Round 4
// 299.254 us; speedup vs baseline: 1.4189x; 1.2008x over previous
//
#include <hip/hip_runtime.h>
#include <hip/hip_bf16.h>

// B=4, N=2048, D_MODEL=512, H=4, DK=64, DV=128. fp32 in/out, bf16 MFMA.
// Softmax over BATCH axis (4 values) -> in-register per lane.
// R4: shared-P attention. wave = (mi, t): t = key-half for S phase, dv-half
// for PV phase. Each wave computes softmax for only 32 keys (no duplication),
// P shared via per-mi double-buffered LDS + one __syncthreads per kt.
// Cheap softmax: 0.125*log2e folded into Wq at prep (S arrives log2-domain),
// no max-sub (|S| small), raw v_rcp, packed v_cvt_pk_bf16_f32.

typedef __attribute__((ext_vector_type(8))) short short8;   // 8 x bf16
typedef __attribute__((ext_vector_type(4))) float floatx4;  // MFMA 16x16 acc
typedef unsigned short u16;
typedef unsigned int u32;

#define MFMA16(a, b, c) __builtin_amdgcn_mfma_f32_16x16x32_bf16((a), (b), (c), 0, 0, 0)

__device__ __forceinline__ u16 f2bf(float f) {
    union { float f; unsigned u; } v; v.f = f;
    unsigned r = v.u + 0x7fffu + ((v.u >> 16) & 1u);  // RNE
    return (u16)(r >> 16);
}

__device__ __forceinline__ u32 pk2bf(float a, float b) {
#if __has_builtin(__builtin_amdgcn_cvt_pk_bf16_f32)
    typedef __attribute__((ext_vector_type(2))) __bf16 bf16x2;
    union { bf16x2 v; u32 u; } c;
    c.v = __builtin_amdgcn_cvt_pk_bf16_f32(a, b);
    return c.u;
#else
    return (u32)f2bf(a) | ((u32)f2bf(b) << 16);
#endif
}

__device__ __forceinline__ float ex2(float x) {
#if __has_builtin(__builtin_amdgcn_exp2f)
    return __builtin_amdgcn_exp2f(x);
#else
    return exp2f(x);
#endif
}

// ---------------- cast fp32 -> bf16 (X, and AOf -> AO) ----------------
__global__ __launch_bounds__(256) void cast_x_kernel(const float* __restrict__ x,
                                                     u16* __restrict__ xb) {
    int i = blockIdx.x * 256 + threadIdx.x;  // 1,048,576 float4 groups exactly
    float4 v = ((const float4*)x)[i];
    ushort4 o;
    o.x = f2bf(v.x); o.y = f2bf(v.y); o.z = f2bf(v.z); o.w = f2bf(v.w);
    ((ushort4*)xb)[i] = o;
}

// ------- weights: fp32 [K][N] -> bf16 transposed [N][K]; Wq|Wk fused -------
// Q columns pre-scaled by 0.125*log2(e) so S = Q@K^T arrives in log2 domain.
__global__ __launch_bounds__(256) void prep_w_kernel(
    const float* __restrict__ Wq, const float* __restrict__ Wk,
    const float* __restrict__ Wv, const float* __restrict__ Wo,
    u16* __restrict__ WqkT, u16* __restrict__ WvT, u16* __restrict__ WoT) {
    int i = blockIdx.x * 256 + threadIdx.x;  // 3 * 512*512 = 786432 exactly
    int plane = i >> 18;
    int j = i & 0x3FFFF;
    int n = j >> 9, k = j & 511;
    if (plane == 0) {
        float v = (n < 256) ? Wq[k * 256 + n] * 0.18033688011f
                            : Wk[k * 256 + (n - 256)];
        WqkT[j] = f2bf(v);
    } else if (plane == 1) {
        WvT[j] = f2bf(Wv[k * 512 + n]);
    } else {
        WoT[j] = f2bf(Wo[k * 512 + n]);
    }
}

// ---------------- GEMM: C[M][N] = A[M][K] * BT[N][K]^T, 64x64 tile --------
// mode 1: fp32 plain (ldc). mode 2: Q plain [8192][256] + K fragment-packed.
// mode 3: V fragment-packed (C is conceptually V^T [512][8192]).
// Kp layout: ((((((b*4+h)*32+kt)*2+half)*2+nj)*2+ki)*64+lane)*8+j
// Vp layout: ((((((b*4+h)*32+kt)*2+half)*4+ni)*2+w)*64+lane)*8+j
__global__ __launch_bounds__(256) void gemm64_kernel(
    const u16* __restrict__ A, const u16* __restrict__ BT,
    float* __restrict__ Cf, u16* __restrict__ Qb, u16* __restrict__ Cp,
    int Kdim, int ldc, int mode) {
    __shared__ u16 Asl[64 * 72];
    __shared__ u16 Bsl[64 * 72];
    const int tid = threadIdx.x;
    const int mbase = blockIdx.y * 64;
    const int nbase = blockIdx.x * 64;
    const int wave = tid >> 6, lane = tid & 63;
    const int wm = wave >> 1, wn = wave & 1;
    const int lq = lane & 15, quad = lane >> 4;

    const floatx4 z4 = {0.f, 0.f, 0.f, 0.f};
    floatx4 acc[2][2];
#pragma unroll
    for (int i = 0; i < 2; i++)
#pragma unroll
        for (int j = 0; j < 2; j++) acc[i][j] = z4;

    const int nk = Kdim >> 6;
    for (int kk = 0; kk < nk; kk++) {
        const int kb = kk << 6;
        if (kk) __syncthreads();
        {   // stage 64x64 of A and BT (8KB each): 2 short8 per thread each
            int row = tid >> 3, cc = (tid & 7) << 3;
            *(short8*)&Asl[row * 72 + cc] =
                *(const short8*)&A[(mbase + row) * Kdim + kb + cc];
            *(short8*)&Bsl[row * 72 + cc] =
                *(const short8*)&BT[(nbase + row) * Kdim + kb + cc];
            int c2 = 256 + tid;
            int row2 = c2 >> 3, cc2 = (c2 & 7) << 3;
            *(short8*)&Asl[row2 * 72 + cc2] =
                *(const short8*)&A[(mbase + row2) * Kdim + kb + cc2];
            *(short8*)&Bsl[row2 * 72 + cc2] =
                *(const short8*)&BT[(nbase + row2) * Kdim + kb + cc2];
        }
        __syncthreads();
#pragma unroll
        for (int ki = 0; ki < 2; ki++) {
            short8 af[2], bf[2];
#pragma unroll
            for (int mi = 0; mi < 2; mi++)
                af[mi] = *(const short8*)&Asl[(wm * 32 + mi * 16 + lq) * 72 + ki * 32 + quad * 8];
#pragma unroll
            for (int ni = 0; ni < 2; ni++)
                bf[ni] = *(const short8*)&Bsl[(wn * 32 + ni * 16 + lq) * 72 + ki * 32 + quad * 8];
#pragma unroll
            for (int mi = 0; mi < 2; mi++)
#pragma unroll
                for (int ni = 0; ni < 2; ni++)
                    acc[mi][ni] = MFMA16(af[mi], bf[ni], acc[mi][ni]);
        }
    }
    // epilogue: C/D layout col=lane&15, row=quad*4+reg (verified m89/m91)
    if (mode == 1) {
#pragma unroll
        for (int mi = 0; mi < 2; mi++)
#pragma unroll
            for (int ni = 0; ni < 2; ni++)
#pragma unroll
                for (int r = 0; r < 4; r++)
                    Cf[(mbase + wm * 32 + mi * 16 + quad * 4 + r) * ldc +
                       (nbase + wn * 32 + ni * 16 + lq)] = acc[mi][ni][r];
    } else if (mode == 2) {
        if (nbase < 256) {  // Q region: plain [8192][256]
#pragma unroll
            for (int mi = 0; mi < 2; mi++)
#pragma unroll
                for (int ni = 0; ni < 2; ni++)
#pragma unroll
                    for (int r = 0; r < 4; r++)
                        Qb[(mbase + wm * 32 + mi * 16 + quad * 4 + r) * 256 +
                           (nbase + wn * 32 + ni * 16 + lq)] = f2bf(acc[mi][ni][r]);
        } else {  // K region -> fragment-packed
#pragma unroll
            for (int mi = 0; mi < 2; mi++)
#pragma unroll
                for (int ni = 0; ni < 2; ni++) {
                    int colk = nbase + wn * 32 + ni * 16 + lq - 256;  // [0,256)
                    int h = colk >> 6, dkc = colk & 63;
                    int ki = dkc >> 5, quadk = (dkc >> 3) & 3, j = dkc & 7;
#pragma unroll
                    for (int r = 0; r < 4; r++) {
                        int row = mbase + wm * 32 + mi * 16 + quad * 4 + r;
                        int b = row >> 11, key = row & 2047;
                        int kt = key >> 6, r6 = key & 63;
                        int half = r6 >> 5, r5 = r6 & 31;
                        int lqk = r5 >> 1, nj = r5 & 1;
                        int lane_k = quadk * 16 + lqk;
                        Cp[((((((((b * 4 + h) * 32 + kt) * 2 + half) * 2 + nj)
                               * 2 + ki) * 64 + lane_k) << 3) + j)] =
                            f2bf(acc[mi][ni][r]);
                    }
                }
        }
    } else {  // mode 3: V fragment-packed; C row = dv, col = b*2048+key
#pragma unroll
        for (int mi = 0; mi < 2; mi++) {
#pragma unroll
            for (int ni = 0; ni < 2; ni++) {
                int col = nbase + wn * 32 + ni * 16 + lq;
                int b = col >> 11, key = col & 2047;
                int kt = key >> 6, rr = key & 63;
                int w = rr >> 5, r5 = rr & 31;
                int quadv = r5 >> 3, j = r5 & 7;
#pragma unroll
                for (int r = 0; r < 4; r++) {
                    int dv = mbase + wm * 32 + mi * 16 + quad * 4 + r;
                    int h = dv >> 7, r7 = dv & 127;
                    int half = r7 >> 6, r6v = r7 & 63;
                    int niv = r6v >> 4, lqv = r6v & 15;
                    int lane_v = quadv * 16 + lqv;
                    Cp[((((((((b * 4 + h) * 32 + kt) * 2 + half) * 4 + niv)
                           * 2 + w) * 64 + lane_v) << 3) + j)] =
                        f2bf(acc[mi][ni][r]);
                }
            }
        }
    }
}

// ---------------- fused attention: shared-P, one barrier per kt ----------
// Grid: 1024 WGs = h(bx&3) x chunk((bx>>2)&3) x qtile(bx>>4, 64 of 32 rows).
// Block: 4 waves; wave = (mi = q-sub16, t = wave>>1). S phase: wave computes
// S+softmax for keys [t*32, t*32+32) only. P -> shared per-mi double-buffered
// LDS; one __syncthreads; PV phase: wave reads full 64-key P, computes its
// dv-half (t). No duplicated softmax/S work.
__global__ __launch_bounds__(256) void attn_kernel(const u16* __restrict__ Qb,
                                                   const u16* __restrict__ Kp,
                                                   const u16* __restrict__ Vp,
                                                   float* __restrict__ AOf) {
    __shared__ u16 pl[2 * 2 * 4 * 16 * 72];  // [buf][mi][b][q16][k72], 36.9KB
    const int bx = blockIdx.x;
    const int h = bx & 3;
    const int ck = (bx >> 2) & 3;
    const int qt = bx >> 4;
    const int tid = threadIdx.x;
    const int wave = tid >> 6, lane = tid & 63;
    const int mi = wave & 1, half = wave >> 1;  // S key-half / PV dv-half
    const int lq = lane & 15, quad = lane >> 4;
    const int q0 = qt * 32 + mi * 16;

    // Q a-frags, persistent: A[m=lane&15][k=quad*8+j]
    short8 aq[4][2];
#pragma unroll
    for (int b = 0; b < 4; b++)
#pragma unroll
        for (int ki = 0; ki < 2; ki++)
            aq[b][ki] = *(const short8*)&Qb[(b * 2048 + q0 + lq) * 256 +
                                            h * 64 + ki * 32 + quad * 8];

    const floatx4 z4 = {0.f, 0.f, 0.f, 0.f};
    floatx4 oacc[4][4];
#pragma unroll
    for (int b = 0; b < 4; b++)
#pragma unroll
        for (int ni = 0; ni < 4; ni++) oacc[b][ni] = z4;

    for (int kt = ck * 8; kt < ck * 8 + 8; kt++) {
        u16* plb = &pl[((kt & 1) * 2 + mi) * (4 * 16 * 72)];
        // ---- S (log2 domain) for this wave's 32 keys, all 4 batches ----
        floatx4 s[4][2];
#pragma unroll
        for (int b = 0; b < 4; b++) {
            const u16* kb = Kp +
                ((size_t)((((b * 4 + h) * 32 + kt) * 2 + half) * 2) << 10) +
                lane * 8;
#pragma unroll
            for (int nj = 0; nj < 2; nj++) {
                s[b][nj] = z4;
#pragma unroll
                for (int ki = 0; ki < 2; ki++)
                    s[b][nj] = MFMA16(aq[b][ki],
                                      *(const short8*)(kb + (nj * 2 + ki) * 512),
                                      s[b][nj]);
            }
        }
        // ---- softmax over batch: e = 2^S (no max-sub; |S| small) ----
        // lane holds S[q=quad*4+r][key = half*32 + 2*lq + nj]
#pragma unroll
        for (int r = 0; r < 4; r++) {
            float e0a = ex2(s[0][0][r]), e0b = ex2(s[0][1][r]);
            float e1a = ex2(s[1][0][r]), e1b = ex2(s[1][1][r]);
            float e2a = ex2(s[2][0][r]), e2b = ex2(s[2][1][r]);
            float e3a = ex2(s[3][0][r]), e3b = ex2(s[3][1][r]);
            float ia = __builtin_amdgcn_rcpf(e0a + e1a + e2a + e3a);
            float ib = __builtin_amdgcn_rcpf(e0b + e1b + e2b + e3b);
            int q = quad * 4 + r, col = half * 32 + 2 * lq;
            *(u32*)&plb[(0 * 16 + q) * 72 + col] = pk2bf(e0a * ia, e0b * ib);
            *(u32*)&plb[(1 * 16 + q) * 72 + col] = pk2bf(e1a * ia, e1b * ib);
            *(u32*)&plb[(2 * 16 + q) * 72 + col] = pk2bf(e2a * ia, e2b * ib);
            *(u32*)&plb[(3 * 16 + q) * 72 + col] = pk2bf(e3a * ia, e3b * ib);
        }
        __syncthreads();  // P complete for both key-halves of this buffer
        // ---- O += P V : full 64 keys, this wave's dv-half ----
#pragma unroll
        for (int b = 0; b < 4; b++) {
            short8 ap0 = *(const short8*)&plb[(b * 16 + lq) * 72 + quad * 8];
            short8 ap1 = *(const short8*)&plb[(b * 16 + lq) * 72 + 32 + quad * 8];
            const u16* vb = Vp +
                ((size_t)((((b * 4 + h) * 32 + kt) * 2 + half) * 8) << 9) +
                lane * 8;
#pragma unroll
            for (int ni = 0; ni < 4; ni++) {
                oacc[b][ni] = MFMA16(ap0, *(const short8*)(vb + (ni * 2 + 0) * 512),
                                     oacc[b][ni]);
                oacc[b][ni] = MFMA16(ap1, *(const short8*)(vb + (ni * 2 + 1) * 512),
                                     oacc[b][ni]);
            }
        }
        // next iteration writes the other buffer -> no second barrier needed
    }
    // ---- epilogue: partial O -> fp32 atomicAdd into AOf[b*2048+q][h*128+d]
#pragma unroll
    for (int b = 0; b < 4; b++)
#pragma unroll
        for (int ni = 0; ni < 4; ni++)
#pragma unroll
            for (int r = 0; r < 4; r++)
                atomicAdd(&AOf[(b * 2048 + q0 + quad * 4 + r) * 512 +
                               h * 128 + half * 64 + ni * 16 + lq],
                          oacc[b][ni][r]);
}

extern "C" void kernel_launch(void* const* d_in, const int* in_sizes, int n_in,
                              void* d_out, int out_size, void* d_ws, size_t ws_size,
                              hipStream_t stream) {
    const float* x  = (const float*)d_in[0];
    const float* Wq = (const float*)d_in[1];
    const float* Wk = (const float*)d_in[2];
    const float* Wv = (const float*)d_in[3];
    const float* Wo = (const float*)d_in[4];
    float* out = (float*)d_out;

    char* ws = (char*)d_ws;
    u16* Xb   = (u16*)ws; ws += (size_t)8192 * 512 * 2;   // X bf16
    u16* WqkT = (u16*)ws; ws += (size_t)512 * 512 * 2;    // [Wq|Wk]^T bf16
    u16* WvT  = (u16*)ws; ws += (size_t)512 * 512 * 2;
    u16* WoT  = (u16*)ws; ws += (size_t)512 * 512 * 2;
    u16* Qb   = (u16*)ws; ws += (size_t)8192 * 256 * 2;   // Q plain [8192][256]
    u16* Kp   = (u16*)ws; ws += (size_t)8192 * 256 * 2;   // K fragment-packed
    u16* Vp   = (u16*)ws; ws += (size_t)8192 * 512 * 2;   // V fragment-packed
    u16* AO   = (u16*)ws; ws += (size_t)8192 * 512 * 2;   // attention out bf16
    float* AOf = (float*)ws; ws += (size_t)8192 * 512 * 4; // fp32 accumulator

    cast_x_kernel<<<4096, 256, 0, stream>>>(x, Xb);
    prep_w_kernel<<<3072, 256, 0, stream>>>(Wq, Wk, Wv, Wo, WqkT, WvT, WoT);
    // QK = X @ [Wq|Wk] : [8192,512] -> Qb plain (pre-scaled) + Kp packed
    gemm64_kernel<<<dim3(8, 128), 256, 0, stream>>>(Xb, WqkT, nullptr, Qb, Kp, 512, 0, 2);
    // V^T = Wv^T @ X^T : [512,8192] -> Vp packed
    gemm64_kernel<<<dim3(128, 8), 256, 0, stream>>>(WvT, Xb, nullptr, nullptr, Vp, 512, 0, 3);
    hipMemsetAsync(AOf, 0, (size_t)8192 * 512 * 4, stream);
    attn_kernel<<<1024, 256, 0, stream>>>(Qb, Kp, Vp, AOf);
    cast_x_kernel<<<4096, 256, 0, stream>>>(AOf, AO);  // fp32 -> bf16
    // out = AO @ Wo : fp32
    gemm64_kernel<<<dim3(8, 128), 256, 0, stream>>>(AO, WoT, out, nullptr, nullptr, 512, 512, 1);
}